// Round 8
// baseline (211.389 us; speedup 1.0000x reference)
//
#include <hip/hip_runtime.h>

// Per-token int4 quantization — verified reference pipeline (R7):
//   scale = fl32( M * fl32(1/7) )                 (combined-constant form)
//   q     = clip(rne(fl32(x / scale)), -8, 7)     (IEEE f32 quotient)
//   byte j = (q[2j+1]&0xF)<<4 | (q[2j]&0xF), stored as float(signed char)
// d_out flat float32: [8192*2048 packed byte values][8192 scales].
//
// One row per WAVE: 64 lanes x 64 elements. No LDS, no __syncthreads —
// butterfly shuffle gives the row max. Per pass p (8 passes), lane handles
// 8 contiguous elements -> 4 packed bytes -> one float4 store (1KB/wave).

constexpr int TOKENS  = 8192;
constexpr int HIDDEN  = 4096;
constexpr int THREADS = 256;                 // 4 waves = 4 rows per block
constexpr int ROWS_PER_BLOCK = THREADS / 64;
constexpr int BLOCKS  = TOKENS / ROWS_PER_BLOCK;
constexpr int PACKED_ROW = HIDDEN / 2;       // 2048 bytes per row
constexpr long long PACKED_TOTAL = (long long)TOKENS * PACKED_ROW;

__global__ __launch_bounds__(THREADS) void quant_i4_kernel(
    const float* __restrict__ x, float* __restrict__ out) {
  const int wave = threadIdx.x >> 6;
  const int lane = threadIdx.x & 63;
  const int row  = blockIdx.x * ROWS_PER_BLOCK + wave;
  const float* __restrict__ xrow = x + (size_t)row * HIDDEN;

  // 8 passes x 8 contiguous elements/lane: two adjacent float4 loads per pass.
  // float4 index: 2*lane + 128*p (+1). 16 loads = 256B in flight per lane.
  float4 v[16];
  float m = 0.0f;
#pragma unroll
  for (int p = 0; p < 8; ++p) {
    v[2 * p]     = reinterpret_cast<const float4*>(xrow)[2 * lane + 128 * p];
    v[2 * p + 1] = reinterpret_cast<const float4*>(xrow)[2 * lane + 1 + 128 * p];
    m = fmaxf(m, fmaxf(fmaxf(fabsf(v[2 * p].x), fabsf(v[2 * p].y)),
                       fmaxf(fabsf(v[2 * p].z), fabsf(v[2 * p].w))));
    m = fmaxf(m, fmaxf(fmaxf(fabsf(v[2 * p + 1].x), fabsf(v[2 * p + 1].y)),
                       fmaxf(fabsf(v[2 * p + 1].z), fabsf(v[2 * p + 1].w))));
  }

  // Wave-64 butterfly max — all lanes end with the row max. No LDS needed.
#pragma unroll
  for (int off = 32; off >= 1; off >>= 1)
    m = fmaxf(m, __shfl_xor(m, off));

  // Verified pipeline: scale = M * fl32(1/7) (f32 multiply).
  const float  rcp7  = (float)(1.0 / 7.0);   // exact fl32(1/7)
  const float  scale = m * rcp7;
  const double sD    = (double)scale;
  const float  rcp   = (float)(1.0 / sD);    // fast path only

  float* __restrict__ orow = out + (size_t)row * PACKED_ROW;
#pragma unroll
  for (int p = 0; p < 8; ++p) {
    float xs[8] = {v[2 * p].x,     v[2 * p].y,     v[2 * p].z,     v[2 * p].w,
                   v[2 * p + 1].x, v[2 * p + 1].y, v[2 * p + 1].z, v[2 * p + 1].w};
    int qi[8];
#pragma unroll
    for (int j = 0; j < 8; ++j) {
      float a = xs[j] * rcp;              // within ~1.4e-6 of true x/scale
      float r = rintf(a);
      if (0.5f - fabsf(a - r) < 1e-5f) {
        // Near a round-half boundary: exact IEEE-f32 quotient via safe f64
        // double rounding (53 >= 2*24+2), then RNE.
        r = rintf((float)((double)xs[j] / sD));
      }
      r = fminf(fmaxf(r, -8.0f), 7.0f);
      qi[j] = (int)r;
    }
    float4 w;
    w.x = (float)(signed char)(((qi[1] & 0xF) << 4) | (qi[0] & 0xF));
    w.y = (float)(signed char)(((qi[3] & 0xF) << 4) | (qi[2] & 0xF));
    w.z = (float)(signed char)(((qi[5] & 0xF) << 4) | (qi[4] & 0xF));
    w.w = (float)(signed char)(((qi[7] & 0xF) << 4) | (qi[6] & 0xF));
    // packed float index 4*lane + 256*p -> float4 index lane + 64*p (1KB/wave)
    reinterpret_cast<float4*>(orow)[lane + 64 * p] = w;
  }

  if (lane == 0) out[PACKED_TOTAL + row] = scale;
}

extern "C" void kernel_launch(void* const* d_in, const int* in_sizes, int n_in,
                              void* d_out, int out_size, void* d_ws, size_t ws_size,
                              hipStream_t stream) {
  const float* x = (const float*)d_in[0];
  float* out = (float*)d_out;
  quant_i4_kernel<<<BLOCKS, THREADS, 0, stream>>>(x, out);
}